// Round 1
// baseline (309.562 us; speedup 1.0000x reference)
//
#include <hip/hip_runtime.h>

// ---------------- problem constants ----------------
#define BATCH 512
#define SDIM  680          // i dimension (680)
#define DIP   768          // i padded to 768 = 24*32 = 6*128
#define ABC   55296        // 48*24*48
#define NB_   24
#define SQRT2F 1.4142135623730951f

typedef __attribute__((ext_vector_type(8))) short bf16x8;
typedef __attribute__((ext_vector_type(4))) float f32x4;

// ws layout (bytes)
#define DP_BYTES   ((size_t)ABC * DIP * 2)            // 84,934,656
#define DPT_BYTES  ((size_t)DIP * ABC * 2)            // 84,934,656
#define FP_BYTES   ((size_t)BATCH * DIP * 2)          //    786,432
#define G_BYTES    ((size_t)BATCH * ABC * 2)          // 56,623,104
#define DP_OFF     ((size_t)0)
#define DPT_OFF    (DP_OFF + DP_BYTES)
#define FP_OFF     (DPT_OFF + DPT_BYTES)
#define G_OFF      (FP_OFF + FP_BYTES)
#define WS_NEEDED  (G_OFF + G_BYTES)                  // 227,278,848

__device__ __forceinline__ unsigned short f2bf(float f) {
  unsigned int u = __float_as_uint(f);
  unsigned int r = (u + 0x7FFFu + ((u >> 16) & 1u)) >> 16;   // RNE
  return (unsigned short)r;
}

__device__ __forceinline__ void stage16(const void* g, const void* l) {
  __builtin_amdgcn_global_load_lds(
      (const __attribute__((address_space(1))) unsigned int*)g,
      (__attribute__((address_space(3))) unsigned int*)l, 16, 0, 0);
}

// ---------------- convert D -> Dp [ABC][DIP] bf16 and DpT [DIP][ABC] bf16 ----------------
// grid: 864 (abc tiles of 64) * 12 (i tiles of 64), 256 threads
__global__ __launch_bounds__(256) void convert_d(const float* __restrict__ D,
                                                 unsigned short* __restrict__ Dp,
                                                 unsigned short* __restrict__ DpT) {
  const int bx = blockIdx.x % 864;   // abc tile
  const int by = blockIdx.x / 864;   // i tile
  __shared__ unsigned short T[64][73];   // pad 73: column reads (stride 8 rows) hit distinct banks
  const int t = threadIdx.x;

  // phase 1: read 64x64 f32 (zero-pad i>=680), write Dp rows + LDS tile
  for (int v = t; v < 1024; v += 256) {
    const int r = v >> 4, q = v & 15;
    const int gi = by * 64 + q * 4;
    const int gr = bx * 64 + r;
    float4 f = make_float4(0.f, 0.f, 0.f, 0.f);
    if (gi < SDIM) f = *(const float4*)(D + (size_t)gr * SDIM + gi);
    unsigned short h0 = f2bf(f.x), h1 = f2bf(f.y), h2 = f2bf(f.z), h3 = f2bf(f.w);
    T[r][q * 4 + 0] = h0; T[r][q * 4 + 1] = h1;
    T[r][q * 4 + 2] = h2; T[r][q * 4 + 3] = h3;
    ushort4 hv; hv.x = h0; hv.y = h1; hv.z = h2; hv.w = h3;
    *(ushort4*)(Dp + (size_t)gr * DIP + gi) = hv;
  }
  __syncthreads();

  // phase 2: transposed writes DpT[i][r], 8 bf16 (16B) per unit
  for (int v = t; v < 512; v += 256) {
    const int il = v >> 3, s = v & 7;
    unsigned int e[8];
    #pragma unroll
    for (int j = 0; j < 8; ++j) e[j] = T[s * 8 + j][il];
    uint4 p;
    p.x = e[0] | (e[1] << 16);
    p.y = e[2] | (e[3] << 16);
    p.z = e[4] | (e[5] << 16);
    p.w = e[6] | (e[7] << 16);
    *(uint4*)(DpT + (size_t)(by * 64 + il) * ABC + bx * 64 + s * 8) = p;
  }
}

// ---------------- convert F -> Fp [BATCH][DIP] bf16 ----------------
// grid 192 * 256 threads; unit = 8 elements
__global__ __launch_bounds__(256) void convert_f(const float* __restrict__ F,
                                                 unsigned short* __restrict__ Fp) {
  const int u = blockIdx.x * 256 + threadIdx.x;   // 512*96 = 49152 units
  if (u >= BATCH * (DIP / 8)) return;
  const int n = u / (DIP / 8), s = u % (DIP / 8);
  const int i = s * 8;
  float4 a = make_float4(0.f, 0.f, 0.f, 0.f), b = a;
  if (i < SDIM) {   // 680 % 8 == 0, so fully valid when i < 680
    a = *(const float4*)(F + (size_t)n * SDIM + i);
    b = *(const float4*)(F + (size_t)n * SDIM + i + 4);
  }
  uint4 p;
  p.x = f2bf(a.x) | ((unsigned int)f2bf(a.y) << 16);
  p.y = f2bf(a.z) | ((unsigned int)f2bf(a.w) << 16);
  p.z = f2bf(b.x) | ((unsigned int)f2bf(b.y) << 16);
  p.w = f2bf(b.z) | ((unsigned int)f2bf(b.w) << 16);
  *(uint4*)(Fp + (size_t)n * DIP + i) = p;
}

// ---------------- GEMM1: G[n][abc] = relu(F·D^T)·sqrt2·qw[b]  (bf16 out) ----------------
// M=512 (Fp rows), N=55296 (Dp rows), K=768. 128x128 tile, BK=32, 4 waves 2x2.
__global__ __launch_bounds__(256) void gemm1(const unsigned short* __restrict__ Fp,
                                             const unsigned short* __restrict__ Dp,
                                             const float* __restrict__ qw,
                                             unsigned short* __restrict__ G) {
  __shared__ short At[2][128 * 32];
  __shared__ short Bt[2][128 * 32];
  __shared__ float qws[NB_];
  const int t = threadIdx.x;
  const int bid = blockIdx.x;            // 432*4
  const int nt = bid >> 2, mt = bid & 3;
  const int m0 = mt * 128, n0 = nt * 128;
  if (t < NB_) qws[t] = qw[t] * SQRT2F;

  const int rowu = t >> 2, k8 = (t & 3) * 8;
  const unsigned short* Ab = Fp + (size_t)(m0 + rowu) * DIP + k8;
  const unsigned short* Bb = Dp + (size_t)(n0 + rowu) * DIP + k8;

  const int lane = t & 63, wid = t >> 6;
  const int wm = wid >> 1, wn = wid & 1;
  const int fr = lane & 15, fk = lane >> 4;

  f32x4 acc[4][4];
  #pragma unroll
  for (int i = 0; i < 4; ++i)
    #pragma unroll
    for (int j = 0; j < 4; ++j)
      #pragma unroll
      for (int k = 0; k < 4; ++k) acc[i][j][k] = 0.f;

  auto stage = [&](int b, int kk) {
    const unsigned short* ga = Ab + kk * 32;
    const unsigned short* gb = Bb + kk * 32;
    stage16(ga,            &At[b][t * 8]);
    stage16(ga + 64 * DIP, &At[b][(t + 256) * 8]);
    stage16(gb,            &Bt[b][t * 8]);
    stage16(gb + 64 * DIP, &Bt[b][(t + 256) * 8]);
  };

  stage(0, 0);
  __syncthreads();
  const int KS = DIP / 32;   // 24
  for (int ks = 0; ks < KS; ++ks) {
    const int cur = ks & 1;
    if (ks + 1 < KS) stage(cur ^ 1, ks + 1);
    bf16x8 af[4], bv[4];
    #pragma unroll
    for (int mi = 0; mi < 4; ++mi)
      af[mi] = *(const bf16x8*)&At[cur][(wm * 64 + mi * 16 + fr) * 32 + fk * 8];
    #pragma unroll
    for (int ni = 0; ni < 4; ++ni)
      bv[ni] = *(const bf16x8*)&Bt[cur][(wn * 64 + ni * 16 + fr) * 32 + fk * 8];
    #pragma unroll
    for (int mi = 0; mi < 4; ++mi)
      #pragma unroll
      for (int ni = 0; ni < 4; ++ni)
        acc[mi][ni] = __builtin_amdgcn_mfma_f32_16x16x32_bf16(af[mi], bv[ni], acc[mi][ni], 0, 0, 0);
    __syncthreads();
  }

  // epilogue: C row = batch m, col = abc; apply relu * sqrt2 * qw[(abc/48)%24]
  #pragma unroll
  for (int mi = 0; mi < 4; ++mi) {
    const int gm0 = m0 + wm * 64 + mi * 16 + fk * 4;
    #pragma unroll
    for (int ni = 0; ni < 4; ++ni) {
      const int gc = n0 + wn * 64 + ni * 16 + fr;
      const float qv = qws[(gc / 48) % NB_];
      #pragma unroll
      for (int r = 0; r < 4; ++r) {
        const float v = fmaxf(acc[mi][ni][r], 0.f) * qv;
        G[(size_t)(gm0 + r) * ABC + gc] = f2bf(v);
      }
    }
  }
}

// ---------------- GEMM2: out[n][i] += sum_k G[n][k] * DpT[i][k]  (split-K, atomic) ----------------
// M=512, N=768 (store only i<680), K=55296 split into 32 chunks of 1728.
__global__ __launch_bounds__(256) void gemm2(const unsigned short* __restrict__ Gm,
                                             const unsigned short* __restrict__ DpT,
                                             float* __restrict__ out) {
  __shared__ short At[2][128 * 32];
  __shared__ short Bt[2][128 * 32];
  const int t = threadIdx.x;
  const int bid = blockIdx.x;            // 32 * 4 * 6 = 768
  const int sk = bid / 24;
  const int rem = bid % 24;
  const int mt = rem / 6, nt = rem % 6;
  const int m0 = mt * 128, n0 = nt * 128;
  const size_t kbase = (size_t)sk * 1728;

  const int rowu = t >> 2, k8 = (t & 3) * 8;
  const unsigned short* Ab = Gm  + (size_t)(m0 + rowu) * ABC + kbase + k8;
  const unsigned short* Bb = DpT + (size_t)(n0 + rowu) * ABC + kbase + k8;

  const int lane = t & 63, wid = t >> 6;
  const int wm = wid >> 1, wn = wid & 1;
  const int fr = lane & 15, fk = lane >> 4;

  f32x4 acc[4][4];
  #pragma unroll
  for (int i = 0; i < 4; ++i)
    #pragma unroll
    for (int j = 0; j < 4; ++j)
      #pragma unroll
      for (int k = 0; k < 4; ++k) acc[i][j][k] = 0.f;

  auto stage = [&](int b, int kk) {
    const unsigned short* ga = Ab + kk * 32;
    const unsigned short* gb = Bb + kk * 32;
    stage16(ga,                    &At[b][t * 8]);
    stage16(ga + (size_t)64 * ABC, &At[b][(t + 256) * 8]);
    stage16(gb,                    &Bt[b][t * 8]);
    stage16(gb + (size_t)64 * ABC, &Bt[b][(t + 256) * 8]);
  };

  stage(0, 0);
  __syncthreads();
  const int KS = 1728 / 32;   // 54
  for (int ks = 0; ks < KS; ++ks) {
    const int cur = ks & 1;
    if (ks + 1 < KS) stage(cur ^ 1, ks + 1);
    bf16x8 af[4], bv[4];
    #pragma unroll
    for (int mi = 0; mi < 4; ++mi)
      af[mi] = *(const bf16x8*)&At[cur][(wm * 64 + mi * 16 + fr) * 32 + fk * 8];
    #pragma unroll
    for (int ni = 0; ni < 4; ++ni)
      bv[ni] = *(const bf16x8*)&Bt[cur][(wn * 64 + ni * 16 + fr) * 32 + fk * 8];
    #pragma unroll
    for (int mi = 0; mi < 4; ++mi)
      #pragma unroll
      for (int ni = 0; ni < 4; ++ni)
        acc[mi][ni] = __builtin_amdgcn_mfma_f32_16x16x32_bf16(af[mi], bv[ni], acc[mi][ni], 0, 0, 0);
    __syncthreads();
  }

  #pragma unroll
  for (int mi = 0; mi < 4; ++mi) {
    const int gm0 = m0 + wm * 64 + mi * 16 + fk * 4;
    #pragma unroll
    for (int ni = 0; ni < 4; ++ni) {
      const int gi = n0 + wn * 64 + ni * 16 + fr;
      if (gi < SDIM) {
        #pragma unroll
        for (int r = 0; r < 4; ++r)
          atomicAdd(&out[(size_t)(gm0 + r) * SDIM + gi], acc[mi][ni][r]);
      }
    }
  }
}

// ---------------- fallback (no workspace needed): slow but correct ----------------
__global__ __launch_bounds__(256) void so3_fallback(const float* __restrict__ F,
                                                    const float* __restrict__ D,
                                                    const float* __restrict__ qw,
                                                    float* __restrict__ out) {
  const int n = blockIdx.x;
  __shared__ float fsh[SDIM];
  __shared__ float acc[SDIM];
  __shared__ float gch[256];
  for (int i = threadIdx.x; i < SDIM; i += 256) {
    fsh[i] = F[(size_t)n * SDIM + i];
    acc[i] = 0.f;
  }
  __syncthreads();
  for (int c0 = 0; c0 < ABC; c0 += 256) {
    const int r = c0 + threadIdx.x;
    const float* dr = D + (size_t)r * SDIM;
    float s = 0.f;
    for (int i = 0; i < SDIM; ++i) s += fsh[i] * dr[i];
    s = fmaxf(s, 0.f) * SQRT2F * qw[(r / 48) % NB_];
    gch[threadIdx.x] = s;
    __syncthreads();
    for (int i = threadIdx.x; i < SDIM; i += 256) {
      float a = 0.f;
      for (int tt = 0; tt < 256; ++tt) a += gch[tt] * D[(size_t)(c0 + tt) * SDIM + i];
      acc[i] += a;
    }
    __syncthreads();
  }
  for (int i = threadIdx.x; i < SDIM; i += 256) out[(size_t)n * SDIM + i] = acc[i];
}

// ---------------- launch ----------------
extern "C" void kernel_launch(void* const* d_in, const int* in_sizes, int n_in,
                              void* d_out, int out_size, void* d_ws, size_t ws_size,
                              hipStream_t stream) {
  const float* F  = (const float*)d_in[0];
  const float* D  = (const float*)d_in[1];
  const float* qw = (const float*)d_in[2];
  float* out = (float*)d_out;

  hipMemsetAsync(d_out, 0, (size_t)out_size * sizeof(float), stream);

  if (ws_size < WS_NEEDED) {
    // insurance path: no workspace available
    so3_fallback<<<BATCH, 256, 0, stream>>>(F, D, qw, out);
    return;
  }

  unsigned short* Dp  = (unsigned short*)((char*)d_ws + DP_OFF);
  unsigned short* DpT = (unsigned short*)((char*)d_ws + DPT_OFF);
  unsigned short* Fp  = (unsigned short*)((char*)d_ws + FP_OFF);
  unsigned short* G   = (unsigned short*)((char*)d_ws + G_OFF);

  convert_d<<<864 * 12, 256, 0, stream>>>(D, Dp, DpT);
  convert_f<<<192, 256, 0, stream>>>(F, Fp);
  gemm1<<<432 * 4, 256, 0, stream>>>(Fp, Dp, qw, G);
  gemm2<<<768, 256, 0, stream>>>(G, DpT, out);
}

// Round 2
// 299.550 us; speedup vs baseline: 1.0334x; 1.0334x over previous
//
#include <hip/hip_runtime.h>

// ---------------- problem constants ----------------
#define BATCH 512
#define SDIM  680          // i dimension (680)
#define DIP   768          // i padded to 768 = 24*32 = 6*128
#define ABC   55296        // 48*24*48
#define NB_   24
#define SQRT2F 1.4142135623730951f

typedef __attribute__((ext_vector_type(8))) short bf16x8;
typedef __attribute__((ext_vector_type(4))) float f32x4;

// ws layout (bytes)
#define DP_BYTES   ((size_t)ABC * DIP * 2)            // 84,934,656
#define DPT_BYTES  ((size_t)DIP * ABC * 2)            // 84,934,656
#define FP_BYTES   ((size_t)BATCH * DIP * 2)          //    786,432
#define G_BYTES    ((size_t)BATCH * ABC * 2)          // 56,623,104
#define DP_OFF     ((size_t)0)
#define DPT_OFF    (DP_OFF + DP_BYTES)
#define FP_OFF     (DPT_OFF + DPT_BYTES)
#define G_OFF      (FP_OFF + FP_BYTES)
#define WS_NEEDED  (G_OFF + G_BYTES)                  // 227,278,848

// gemm2 split-K config
#define SPLITK 64
#define KC     864          // 55296 / 64; 864/32 = 27 K-steps

__device__ __forceinline__ unsigned short f2bf(float f) {
  unsigned int u = __float_as_uint(f);
  unsigned int r = (u + 0x7FFFu + ((u >> 16) & 1u)) >> 16;   // RNE
  return (unsigned short)r;
}

__device__ __forceinline__ void stage16(const void* g, const void* l) {
  __builtin_amdgcn_global_load_lds(
      (const __attribute__((address_space(1))) unsigned int*)g,
      (__attribute__((address_space(3))) unsigned int*)l, 16, 0, 0);
}

// ---------------- convert D -> Dp [ABC][DIP] bf16 and DpT [DIP][ABC] bf16 ----------------
// grid: 864 (abc tiles of 64) * 12 (i tiles of 64), 256 threads
__global__ __launch_bounds__(256) void convert_d(const float* __restrict__ D,
                                                 unsigned short* __restrict__ Dp,
                                                 unsigned short* __restrict__ DpT) {
  const int bx = blockIdx.x % 864;   // abc tile
  const int by = blockIdx.x / 864;   // i tile
  __shared__ unsigned short T[64][73];   // pad 73: column reads (stride 8 rows) hit distinct banks
  const int t = threadIdx.x;

  // phase 1: read 64x64 f32 (zero-pad i>=680), write Dp rows + LDS tile
  for (int v = t; v < 1024; v += 256) {
    const int r = v >> 4, q = v & 15;
    const int gi = by * 64 + q * 4;
    const int gr = bx * 64 + r;
    float4 f = make_float4(0.f, 0.f, 0.f, 0.f);
    if (gi < SDIM) f = *(const float4*)(D + (size_t)gr * SDIM + gi);
    unsigned short h0 = f2bf(f.x), h1 = f2bf(f.y), h2 = f2bf(f.z), h3 = f2bf(f.w);
    T[r][q * 4 + 0] = h0; T[r][q * 4 + 1] = h1;
    T[r][q * 4 + 2] = h2; T[r][q * 4 + 3] = h3;
    ushort4 hv; hv.x = h0; hv.y = h1; hv.z = h2; hv.w = h3;
    *(ushort4*)(Dp + (size_t)gr * DIP + gi) = hv;
  }
  __syncthreads();

  // phase 2: transposed writes DpT[i][r], 8 bf16 (16B) per unit
  for (int v = t; v < 512; v += 256) {
    const int il = v >> 3, s = v & 7;
    unsigned int e[8];
    #pragma unroll
    for (int j = 0; j < 8; ++j) e[j] = T[s * 8 + j][il];
    uint4 p;
    p.x = e[0] | (e[1] << 16);
    p.y = e[2] | (e[3] << 16);
    p.z = e[4] | (e[5] << 16);
    p.w = e[6] | (e[7] << 16);
    *(uint4*)(DpT + (size_t)(by * 64 + il) * ABC + bx * 64 + s * 8) = p;
  }
}

// ---------------- convert F -> Fp [BATCH][DIP] bf16 ----------------
__global__ __launch_bounds__(256) void convert_f(const float* __restrict__ F,
                                                 unsigned short* __restrict__ Fp) {
  const int u = blockIdx.x * 256 + threadIdx.x;   // 512*96 = 49152 units
  if (u >= BATCH * (DIP / 8)) return;
  const int n = u / (DIP / 8), s = u % (DIP / 8);
  const int i = s * 8;
  float4 a = make_float4(0.f, 0.f, 0.f, 0.f), b = a;
  if (i < SDIM) {   // 680 % 8 == 0, so fully valid when i < 680
    a = *(const float4*)(F + (size_t)n * SDIM + i);
    b = *(const float4*)(F + (size_t)n * SDIM + i + 4);
  }
  uint4 p;
  p.x = f2bf(a.x) | ((unsigned int)f2bf(a.y) << 16);
  p.y = f2bf(a.z) | ((unsigned int)f2bf(a.w) << 16);
  p.z = f2bf(b.x) | ((unsigned int)f2bf(b.y) << 16);
  p.w = f2bf(b.z) | ((unsigned int)f2bf(b.w) << 16);
  *(uint4*)(Fp + (size_t)n * DIP + i) = p;
}

// ---------------- GEMM1: G[n][abc] = relu(F·D^T)·sqrt2·qw[b]  (bf16 out) ----------------
// M=512 (Fp rows), N=55296 (Dp rows), K=768. 128x128 tile, BK=32, 4 waves 2x2.
// XCD-chunked swizzle: 1728 blocks, 216 per XCD; inner order nt-major so the
// 4 mt-blocks sharing a Dp B-tile are L2-co-resident.
__global__ __launch_bounds__(256) void gemm1(const unsigned short* __restrict__ Fp,
                                             const unsigned short* __restrict__ Dp,
                                             const float* __restrict__ qw,
                                             unsigned short* __restrict__ G) {
  __shared__ short At[2][128 * 32];
  __shared__ short Bt[2][128 * 32];
  __shared__ float qws[NB_];
  const int t = threadIdx.x;
  const int bid = blockIdx.x;            // 1728 = 8 XCD * 216
  const int logical = (bid & 7) * 216 + (bid >> 3);
  const int nt = logical >> 2, mt = logical & 3;
  const int m0 = mt * 128, n0 = nt * 128;
  if (t < NB_) qws[t] = qw[t] * SQRT2F;

  const int rowu = t >> 2, k8 = (t & 3) * 8;
  const unsigned short* Ab = Fp + (size_t)(m0 + rowu) * DIP + k8;
  const unsigned short* Bb = Dp + (size_t)(n0 + rowu) * DIP + k8;

  const int lane = t & 63, wid = t >> 6;
  const int wm = wid >> 1, wn = wid & 1;
  const int fr = lane & 15, fk = lane >> 4;

  f32x4 acc[4][4];
  #pragma unroll
  for (int i = 0; i < 4; ++i)
    #pragma unroll
    for (int j = 0; j < 4; ++j)
      #pragma unroll
      for (int k = 0; k < 4; ++k) acc[i][j][k] = 0.f;

  auto stage = [&](int b, int kk) {
    const unsigned short* ga = Ab + kk * 32;
    const unsigned short* gb = Bb + kk * 32;
    stage16(ga,            &At[b][t * 8]);
    stage16(ga + 64 * DIP, &At[b][(t + 256) * 8]);
    stage16(gb,            &Bt[b][t * 8]);
    stage16(gb + 64 * DIP, &Bt[b][(t + 256) * 8]);
  };

  stage(0, 0);
  __syncthreads();
  const int KS = DIP / 32;   // 24
  for (int ks = 0; ks < KS; ++ks) {
    const int cur = ks & 1;
    if (ks + 1 < KS) stage(cur ^ 1, ks + 1);
    bf16x8 af[4], bv[4];
    #pragma unroll
    for (int mi = 0; mi < 4; ++mi)
      af[mi] = *(const bf16x8*)&At[cur][(wm * 64 + mi * 16 + fr) * 32 + fk * 8];
    #pragma unroll
    for (int ni = 0; ni < 4; ++ni)
      bv[ni] = *(const bf16x8*)&Bt[cur][(wn * 64 + ni * 16 + fr) * 32 + fk * 8];
    #pragma unroll
    for (int mi = 0; mi < 4; ++mi)
      #pragma unroll
      for (int ni = 0; ni < 4; ++ni)
        acc[mi][ni] = __builtin_amdgcn_mfma_f32_16x16x32_bf16(af[mi], bv[ni], acc[mi][ni], 0, 0, 0);
    __syncthreads();
  }

  // epilogue: C row = batch m, col = abc; apply relu * sqrt2 * qw[(abc/48)%24]
  #pragma unroll
  for (int mi = 0; mi < 4; ++mi) {
    const int gm0 = m0 + wm * 64 + mi * 16 + fk * 4;
    #pragma unroll
    for (int ni = 0; ni < 4; ++ni) {
      const int gc = n0 + wn * 64 + ni * 16 + fr;
      const float qv = qws[(gc / 48) % NB_];
      #pragma unroll
      for (int r = 0; r < 4; ++r) {
        const float v = fmaxf(acc[mi][ni][r], 0.f) * qv;
        G[(size_t)(gm0 + r) * ABC + gc] = f2bf(v);
      }
    }
  }
}

// ---------------- GEMM2: out[n][i] += sum_k G[n][k] * DpT[i][k]  (split-K, atomic) ----------------
// M=512, N=768 (store only i<680), K=55296 split into 64 chunks of 864.
// 1536 blocks = 6/CU for TLP latency hiding; XCD-chunked swizzle (192/XCD),
// inner order sk -> nt -> mt so one sk-chunk's 4 A-panels + 6 B-panels
// (2.2 MB) are co-resident in the XCD's 4 MB L2.
__global__ __launch_bounds__(256) void gemm2(const unsigned short* __restrict__ Gm,
                                             const unsigned short* __restrict__ DpT,
                                             float* __restrict__ out) {
  __shared__ short At[2][128 * 32];
  __shared__ short Bt[2][128 * 32];
  const int t = threadIdx.x;
  const int bid = blockIdx.x;            // SPLITK * 24 = 1536 = 8 XCD * 192
  const int logical = (bid & 7) * 192 + (bid >> 3);
  const int sk = logical / 24;
  const int rem = logical % 24;
  const int nt = rem >> 2, mt = rem & 3;
  const int m0 = mt * 128, n0 = nt * 128;
  const size_t kbase = (size_t)sk * KC;

  const int rowu = t >> 2, k8 = (t & 3) * 8;
  const unsigned short* Ab = Gm  + (size_t)(m0 + rowu) * ABC + kbase + k8;
  const unsigned short* Bb = DpT + (size_t)(n0 + rowu) * ABC + kbase + k8;

  const int lane = t & 63, wid = t >> 6;
  const int wm = wid >> 1, wn = wid & 1;
  const int fr = lane & 15, fk = lane >> 4;

  f32x4 acc[4][4];
  #pragma unroll
  for (int i = 0; i < 4; ++i)
    #pragma unroll
    for (int j = 0; j < 4; ++j)
      #pragma unroll
      for (int k = 0; k < 4; ++k) acc[i][j][k] = 0.f;

  auto stage = [&](int b, int kk) {
    const unsigned short* ga = Ab + kk * 32;
    const unsigned short* gb = Bb + kk * 32;
    stage16(ga,                    &At[b][t * 8]);
    stage16(ga + (size_t)64 * ABC, &At[b][(t + 256) * 8]);
    stage16(gb,                    &Bt[b][t * 8]);
    stage16(gb + (size_t)64 * ABC, &Bt[b][(t + 256) * 8]);
  };

  stage(0, 0);
  __syncthreads();
  const int KS = KC / 32;   // 27
  for (int ks = 0; ks < KS; ++ks) {
    const int cur = ks & 1;
    if (ks + 1 < KS) stage(cur ^ 1, ks + 1);
    bf16x8 af[4], bv[4];
    #pragma unroll
    for (int mi = 0; mi < 4; ++mi)
      af[mi] = *(const bf16x8*)&At[cur][(wm * 64 + mi * 16 + fr) * 32 + fk * 8];
    #pragma unroll
    for (int ni = 0; ni < 4; ++ni)
      bv[ni] = *(const bf16x8*)&Bt[cur][(wn * 64 + ni * 16 + fr) * 32 + fk * 8];
    #pragma unroll
    for (int mi = 0; mi < 4; ++mi)
      #pragma unroll
      for (int ni = 0; ni < 4; ++ni)
        acc[mi][ni] = __builtin_amdgcn_mfma_f32_16x16x32_bf16(af[mi], bv[ni], acc[mi][ni], 0, 0, 0);
    __syncthreads();
  }

  #pragma unroll
  for (int mi = 0; mi < 4; ++mi) {
    const int gm0 = m0 + wm * 64 + mi * 16 + fk * 4;
    #pragma unroll
    for (int ni = 0; ni < 4; ++ni) {
      const int gi = n0 + wn * 64 + ni * 16 + fr;
      if (gi < SDIM) {
        #pragma unroll
        for (int r = 0; r < 4; ++r)
          atomicAdd(&out[(size_t)(gm0 + r) * SDIM + gi], acc[mi][ni][r]);
      }
    }
  }
}

// ---------------- fallback (no workspace needed): slow but correct ----------------
__global__ __launch_bounds__(256) void so3_fallback(const float* __restrict__ F,
                                                    const float* __restrict__ D,
                                                    const float* __restrict__ qw,
                                                    float* __restrict__ out) {
  const int n = blockIdx.x;
  __shared__ float fsh[SDIM];
  __shared__ float acc[SDIM];
  __shared__ float gch[256];
  for (int i = threadIdx.x; i < SDIM; i += 256) {
    fsh[i] = F[(size_t)n * SDIM + i];
    acc[i] = 0.f;
  }
  __syncthreads();
  for (int c0 = 0; c0 < ABC; c0 += 256) {
    const int r = c0 + threadIdx.x;
    const float* dr = D + (size_t)r * SDIM;
    float s = 0.f;
    for (int i = 0; i < SDIM; ++i) s += fsh[i] * dr[i];
    s = fmaxf(s, 0.f) * SQRT2F * qw[(r / 48) % NB_];
    gch[threadIdx.x] = s;
    __syncthreads();
    for (int i = threadIdx.x; i < SDIM; i += 256) {
      float a = 0.f;
      for (int tt = 0; tt < 256; ++tt) a += gch[tt] * D[(size_t)(c0 + tt) * SDIM + i];
      acc[i] += a;
    }
    __syncthreads();
  }
  for (int i = threadIdx.x; i < SDIM; i += 256) out[(size_t)n * SDIM + i] = acc[i];
}

// ---------------- launch ----------------
extern "C" void kernel_launch(void* const* d_in, const int* in_sizes, int n_in,
                              void* d_out, int out_size, void* d_ws, size_t ws_size,
                              hipStream_t stream) {
  const float* F  = (const float*)d_in[0];
  const float* D  = (const float*)d_in[1];
  const float* qw = (const float*)d_in[2];
  float* out = (float*)d_out;

  hipMemsetAsync(d_out, 0, (size_t)out_size * sizeof(float), stream);

  if (ws_size < WS_NEEDED) {
    // insurance path: no workspace available
    so3_fallback<<<BATCH, 256, 0, stream>>>(F, D, qw, out);
    return;
  }

  unsigned short* Dp  = (unsigned short*)((char*)d_ws + DP_OFF);
  unsigned short* DpT = (unsigned short*)((char*)d_ws + DPT_OFF);
  unsigned short* Fp  = (unsigned short*)((char*)d_ws + FP_OFF);
  unsigned short* G   = (unsigned short*)((char*)d_ws + G_OFF);

  convert_d<<<864 * 12, 256, 0, stream>>>(D, Dp, DpT);
  convert_f<<<192, 256, 0, stream>>>(F, Fp);
  gemm1<<<432 * 4, 256, 0, stream>>>(Fp, Dp, qw, G);
  gemm2<<<SPLITK * 24, 256, 0, stream>>>(G, DpT, out);
}

// Round 3
// 236.142 us; speedup vs baseline: 1.3109x; 1.2685x over previous
//
#include <hip/hip_runtime.h>

// ---------------- problem constants ----------------
#define BATCH 512
#define SDIM  680          // i dimension (680)
#define DIP   768          // i padded to 768 = 24*32 = 6*128
#define ABC   55296        // 48*24*48
#define NB_   24
#define SQRT2F 1.4142135623730951f

typedef __attribute__((ext_vector_type(8))) short bf16x8;
typedef __attribute__((ext_vector_type(4))) float f32x4;

// ws layout (bytes)
#define DP_BYTES   ((size_t)ABC * DIP * 2)            // 84,934,656
#define DPT_BYTES  ((size_t)DIP * ABC * 2)            // 84,934,656
#define FP_BYTES   ((size_t)BATCH * DIP * 2)          //    786,432
#define G_BYTES    ((size_t)BATCH * ABC * 2)          // 56,623,104
#define DP_OFF     ((size_t)0)
#define DPT_OFF    (DP_OFF + DP_BYTES)
#define FP_OFF     (DPT_OFF + DPT_BYTES)
#define G_OFF      (FP_OFF + FP_BYTES)
#define WS_NEEDED  (G_OFF + G_BYTES)                  // 227,278,848

// gemm2 split-K config: 55296 = 54 * 1024
#define SPLITK 54
#define KC     1024
// partials P[SPLITK][512][768] f32 = 54*512*768*4 = 84,934,656 B == DP_BYTES,
// placed over the Dp region (dead after gemm1; stream order serializes).
#define P_OFF  DP_OFF

__device__ __forceinline__ unsigned short f2bf(float f) {
  unsigned int u = __float_as_uint(f);
  unsigned int r = (u + 0x7FFFu + ((u >> 16) & 1u)) >> 16;   // RNE
  return (unsigned short)r;
}

__device__ __forceinline__ void stage16(const void* g, const void* l) {
  __builtin_amdgcn_global_load_lds(
      (const __attribute__((address_space(1))) unsigned int*)g,
      (__attribute__((address_space(3))) unsigned int*)l, 16, 0, 0);
}

// ---------------- convert D -> Dp [ABC][DIP] bf16 and DpT [DIP][ABC] bf16 ----------------
__global__ __launch_bounds__(256) void convert_d(const float* __restrict__ D,
                                                 unsigned short* __restrict__ Dp,
                                                 unsigned short* __restrict__ DpT) {
  const int bx = blockIdx.x % 864;   // abc tile
  const int by = blockIdx.x / 864;   // i tile
  __shared__ unsigned short T[64][73];
  const int t = threadIdx.x;

  for (int v = t; v < 1024; v += 256) {
    const int r = v >> 4, q = v & 15;
    const int gi = by * 64 + q * 4;
    const int gr = bx * 64 + r;
    float4 f = make_float4(0.f, 0.f, 0.f, 0.f);
    if (gi < SDIM) f = *(const float4*)(D + (size_t)gr * SDIM + gi);
    unsigned short h0 = f2bf(f.x), h1 = f2bf(f.y), h2 = f2bf(f.z), h3 = f2bf(f.w);
    T[r][q * 4 + 0] = h0; T[r][q * 4 + 1] = h1;
    T[r][q * 4 + 2] = h2; T[r][q * 4 + 3] = h3;
    ushort4 hv; hv.x = h0; hv.y = h1; hv.z = h2; hv.w = h3;
    *(ushort4*)(Dp + (size_t)gr * DIP + gi) = hv;
  }
  __syncthreads();

  for (int v = t; v < 512; v += 256) {
    const int il = v >> 3, s = v & 7;
    unsigned int e[8];
    #pragma unroll
    for (int j = 0; j < 8; ++j) e[j] = T[s * 8 + j][il];
    uint4 p;
    p.x = e[0] | (e[1] << 16);
    p.y = e[2] | (e[3] << 16);
    p.z = e[4] | (e[5] << 16);
    p.w = e[6] | (e[7] << 16);
    *(uint4*)(DpT + (size_t)(by * 64 + il) * ABC + bx * 64 + s * 8) = p;
  }
}

// ---------------- convert F -> Fp [BATCH][DIP] bf16 ----------------
__global__ __launch_bounds__(256) void convert_f(const float* __restrict__ F,
                                                 unsigned short* __restrict__ Fp) {
  const int u = blockIdx.x * 256 + threadIdx.x;
  if (u >= BATCH * (DIP / 8)) return;
  const int n = u / (DIP / 8), s = u % (DIP / 8);
  const int i = s * 8;
  float4 a = make_float4(0.f, 0.f, 0.f, 0.f), b = a;
  if (i < SDIM) {
    a = *(const float4*)(F + (size_t)n * SDIM + i);
    b = *(const float4*)(F + (size_t)n * SDIM + i + 4);
  }
  uint4 p;
  p.x = f2bf(a.x) | ((unsigned int)f2bf(a.y) << 16);
  p.y = f2bf(a.z) | ((unsigned int)f2bf(a.w) << 16);
  p.z = f2bf(b.x) | ((unsigned int)f2bf(b.y) << 16);
  p.w = f2bf(b.z) | ((unsigned int)f2bf(b.w) << 16);
  *(uint4*)(Fp + (size_t)n * DIP + i) = p;
}

// ---------------- GEMM1: G[n][abc] = relu(F·D^T)·sqrt2·qw[b]  (bf16 out) ----------------
__global__ __launch_bounds__(256) void gemm1(const unsigned short* __restrict__ Fp,
                                             const unsigned short* __restrict__ Dp,
                                             const float* __restrict__ qw,
                                             unsigned short* __restrict__ G) {
  __shared__ short At[2][128 * 32];
  __shared__ short Bt[2][128 * 32];
  __shared__ float qws[NB_];
  const int t = threadIdx.x;
  const int bid = blockIdx.x;            // 1728 = 8 XCD * 216
  const int logical = (bid & 7) * 216 + (bid >> 3);
  const int nt = logical >> 2, mt = logical & 3;
  const int m0 = mt * 128, n0 = nt * 128;
  if (t < NB_) qws[t] = qw[t] * SQRT2F;

  const int rowu = t >> 2, k8 = (t & 3) * 8;
  const unsigned short* Ab = Fp + (size_t)(m0 + rowu) * DIP + k8;
  const unsigned short* Bb = Dp + (size_t)(n0 + rowu) * DIP + k8;

  const int lane = t & 63, wid = t >> 6;
  const int wm = wid >> 1, wn = wid & 1;
  const int fr = lane & 15, fk = lane >> 4;

  f32x4 acc[4][4];
  #pragma unroll
  for (int i = 0; i < 4; ++i)
    #pragma unroll
    for (int j = 0; j < 4; ++j)
      #pragma unroll
      for (int k = 0; k < 4; ++k) acc[i][j][k] = 0.f;

  auto stage = [&](int b, int kk) {
    const unsigned short* ga = Ab + kk * 32;
    const unsigned short* gb = Bb + kk * 32;
    stage16(ga,            &At[b][t * 8]);
    stage16(ga + 64 * DIP, &At[b][(t + 256) * 8]);
    stage16(gb,            &Bt[b][t * 8]);
    stage16(gb + 64 * DIP, &Bt[b][(t + 256) * 8]);
  };

  stage(0, 0);
  __syncthreads();
  const int KS = DIP / 32;   // 24
  for (int ks = 0; ks < KS; ++ks) {
    const int cur = ks & 1;
    if (ks + 1 < KS) stage(cur ^ 1, ks + 1);
    bf16x8 af[4], bv[4];
    #pragma unroll
    for (int mi = 0; mi < 4; ++mi)
      af[mi] = *(const bf16x8*)&At[cur][(wm * 64 + mi * 16 + fr) * 32 + fk * 8];
    #pragma unroll
    for (int ni = 0; ni < 4; ++ni)
      bv[ni] = *(const bf16x8*)&Bt[cur][(wn * 64 + ni * 16 + fr) * 32 + fk * 8];
    #pragma unroll
    for (int mi = 0; mi < 4; ++mi)
      #pragma unroll
      for (int ni = 0; ni < 4; ++ni)
        acc[mi][ni] = __builtin_amdgcn_mfma_f32_16x16x32_bf16(af[mi], bv[ni], acc[mi][ni], 0, 0, 0);
    __syncthreads();
  }

  #pragma unroll
  for (int mi = 0; mi < 4; ++mi) {
    const int gm0 = m0 + wm * 64 + mi * 16 + fk * 4;
    #pragma unroll
    for (int ni = 0; ni < 4; ++ni) {
      const int gc = n0 + wn * 64 + ni * 16 + fr;
      const float qv = qws[(gc / 48) % NB_];
      #pragma unroll
      for (int r = 0; r < 4; ++r) {
        const float v = fmaxf(acc[mi][ni][r], 0.f) * qv;
        G[(size_t)(gm0 + r) * ABC + gc] = f2bf(v);
      }
    }
  }
}

// ---------------- GEMM2: P[sk][n][i] = sum_{k in chunk sk} G[n][k] * DpT[i][k] ----------------
// Deterministic split-K: NO atomics. 54 chunks of 1024 (32 K-steps).
// Grid 1296 = 54*24; XCD swizzle (162/XCD), inner order sk -> nt -> mt so one
// sk-chunk's 4 A-panels + 6 B-panels (2.5 MB) are L2-co-resident.
__global__ __launch_bounds__(256) void gemm2(const unsigned short* __restrict__ Gm,
                                             const unsigned short* __restrict__ DpT,
                                             float* __restrict__ P) {
  __shared__ short At[2][128 * 32];
  __shared__ short Bt[2][128 * 32];
  const int t = threadIdx.x;
  const int bid = blockIdx.x;            // 1296 = 8 XCD * 162
  const int logical = (bid & 7) * 162 + (bid >> 3);
  const int sk = logical / 24;
  const int rem = logical % 24;
  const int nt = rem >> 2, mt = rem & 3;
  const int m0 = mt * 128, n0 = nt * 128;
  const size_t kbase = (size_t)sk * KC;

  const int rowu = t >> 2, k8 = (t & 3) * 8;
  const unsigned short* Ab = Gm  + (size_t)(m0 + rowu) * ABC + kbase + k8;
  const unsigned short* Bb = DpT + (size_t)(n0 + rowu) * ABC + kbase + k8;

  const int lane = t & 63, wid = t >> 6;
  const int wm = wid >> 1, wn = wid & 1;
  const int fr = lane & 15, fk = lane >> 4;

  f32x4 acc[4][4];
  #pragma unroll
  for (int i = 0; i < 4; ++i)
    #pragma unroll
    for (int j = 0; j < 4; ++j)
      #pragma unroll
      for (int k = 0; k < 4; ++k) acc[i][j][k] = 0.f;

  auto stage = [&](int b, int kk) {
    const unsigned short* ga = Ab + kk * 32;
    const unsigned short* gb = Bb + kk * 32;
    stage16(ga,                    &At[b][t * 8]);
    stage16(ga + (size_t)64 * ABC, &At[b][(t + 256) * 8]);
    stage16(gb,                    &Bt[b][t * 8]);
    stage16(gb + (size_t)64 * ABC, &Bt[b][(t + 256) * 8]);
  };

  stage(0, 0);
  __syncthreads();
  const int KS = KC / 32;   // 32
  for (int ks = 0; ks < KS; ++ks) {
    const int cur = ks & 1;
    if (ks + 1 < KS) stage(cur ^ 1, ks + 1);
    bf16x8 af[4], bv[4];
    #pragma unroll
    for (int mi = 0; mi < 4; ++mi)
      af[mi] = *(const bf16x8*)&At[cur][(wm * 64 + mi * 16 + fr) * 32 + fk * 8];
    #pragma unroll
    for (int ni = 0; ni < 4; ++ni)
      bv[ni] = *(const bf16x8*)&Bt[cur][(wn * 64 + ni * 16 + fr) * 32 + fk * 8];
    #pragma unroll
    for (int mi = 0; mi < 4; ++mi)
      #pragma unroll
      for (int ni = 0; ni < 4; ++ni)
        acc[mi][ni] = __builtin_amdgcn_mfma_f32_16x16x32_bf16(af[mi], bv[ni], acc[mi][ni], 0, 0, 0);
    __syncthreads();
  }

  // plain f32 stores to this split's partial tile (full 768 width, no mask)
  float* Pb = P + (size_t)sk * BATCH * DIP;
  #pragma unroll
  for (int mi = 0; mi < 4; ++mi) {
    const int gm0 = m0 + wm * 64 + mi * 16 + fk * 4;
    #pragma unroll
    for (int ni = 0; ni < 4; ++ni) {
      const int gi = n0 + wn * 64 + ni * 16 + fr;
      #pragma unroll
      for (int r = 0; r < 4; ++r)
        Pb[(size_t)(gm0 + r) * DIP + gi] = acc[mi][ni][r];
    }
  }
}

// ---------------- reduce: out[n][i] = sum_s P[s][n][i]  (i < 680) ----------------
// 87040 float4 units = 340 blocks * 256 threads; 6-way MLP unroll over splits.
__global__ __launch_bounds__(256) void reduce_p(const float* __restrict__ P,
                                                float* __restrict__ out) {
  const int u = blockIdx.x * 256 + threadIdx.x;   // 512 * 170
  const int n = u / (SDIM / 4), q = u % (SDIM / 4);
  const int i = q * 4;
  const float* base = P + (size_t)n * DIP + i;
  const size_t stride = (size_t)BATCH * DIP;
  float4 a0 = make_float4(0.f, 0.f, 0.f, 0.f), a1 = a0, a2 = a0, a3 = a0, a4 = a0, a5 = a0;
  #pragma unroll 3
  for (int s = 0; s < SPLITK; s += 6) {
    float4 v0 = *(const float4*)(base + (size_t)(s + 0) * stride);
    float4 v1 = *(const float4*)(base + (size_t)(s + 1) * stride);
    float4 v2 = *(const float4*)(base + (size_t)(s + 2) * stride);
    float4 v3 = *(const float4*)(base + (size_t)(s + 3) * stride);
    float4 v4 = *(const float4*)(base + (size_t)(s + 4) * stride);
    float4 v5 = *(const float4*)(base + (size_t)(s + 5) * stride);
    a0.x += v0.x; a0.y += v0.y; a0.z += v0.z; a0.w += v0.w;
    a1.x += v1.x; a1.y += v1.y; a1.z += v1.z; a1.w += v1.w;
    a2.x += v2.x; a2.y += v2.y; a2.z += v2.z; a2.w += v2.w;
    a3.x += v3.x; a3.y += v3.y; a3.z += v3.z; a3.w += v3.w;
    a4.x += v4.x; a4.y += v4.y; a4.z += v4.z; a4.w += v4.w;
    a5.x += v5.x; a5.y += v5.y; a5.z += v5.z; a5.w += v5.w;
  }
  float4 r;
  r.x = ((a0.x + a1.x) + (a2.x + a3.x)) + (a4.x + a5.x);
  r.y = ((a0.y + a1.y) + (a2.y + a3.y)) + (a4.y + a5.y);
  r.z = ((a0.z + a1.z) + (a2.z + a3.z)) + (a4.z + a5.z);
  r.w = ((a0.w + a1.w) + (a2.w + a3.w)) + (a4.w + a5.w);
  *(float4*)(out + (size_t)n * SDIM + i) = r;
}

// ---------------- fallback (no workspace needed): slow but correct ----------------
__global__ __launch_bounds__(256) void so3_fallback(const float* __restrict__ F,
                                                    const float* __restrict__ D,
                                                    const float* __restrict__ qw,
                                                    float* __restrict__ out) {
  const int n = blockIdx.x;
  __shared__ float fsh[SDIM];
  __shared__ float acc[SDIM];
  __shared__ float gch[256];
  for (int i = threadIdx.x; i < SDIM; i += 256) {
    fsh[i] = F[(size_t)n * SDIM + i];
    acc[i] = 0.f;
  }
  __syncthreads();
  for (int c0 = 0; c0 < ABC; c0 += 256) {
    const int r = c0 + threadIdx.x;
    const float* dr = D + (size_t)r * SDIM;
    float s = 0.f;
    for (int i = 0; i < SDIM; ++i) s += fsh[i] * dr[i];
    s = fmaxf(s, 0.f) * SQRT2F * qw[(r / 48) % NB_];
    gch[threadIdx.x] = s;
    __syncthreads();
    for (int i = threadIdx.x; i < SDIM; i += 256) {
      float a = 0.f;
      for (int tt = 0; tt < 256; ++tt) a += gch[tt] * D[(size_t)(c0 + tt) * SDIM + i];
      acc[i] += a;
    }
    __syncthreads();
  }
  for (int i = threadIdx.x; i < SDIM; i += 256) out[(size_t)n * SDIM + i] = acc[i];
}

// ---------------- launch ----------------
extern "C" void kernel_launch(void* const* d_in, const int* in_sizes, int n_in,
                              void* d_out, int out_size, void* d_ws, size_t ws_size,
                              hipStream_t stream) {
  const float* F  = (const float*)d_in[0];
  const float* D  = (const float*)d_in[1];
  const float* qw = (const float*)d_in[2];
  float* out = (float*)d_out;

  if (ws_size < WS_NEEDED) {
    // insurance path: no workspace available
    so3_fallback<<<BATCH, 256, 0, stream>>>(F, D, qw, out);
    return;
  }

  unsigned short* Dp  = (unsigned short*)((char*)d_ws + DP_OFF);
  unsigned short* DpT = (unsigned short*)((char*)d_ws + DPT_OFF);
  unsigned short* Fp  = (unsigned short*)((char*)d_ws + FP_OFF);
  unsigned short* G   = (unsigned short*)((char*)d_ws + G_OFF);
  float*          P   = (float*)((char*)d_ws + P_OFF);   // overlays Dp (dead after gemm1)

  convert_d<<<864 * 12, 256, 0, stream>>>(D, Dp, DpT);
  convert_f<<<192, 256, 0, stream>>>(F, Fp);
  gemm1<<<432 * 4, 256, 0, stream>>>(Fp, Dp, qw, G);
  gemm2<<<SPLITK * 24, 256, 0, stream>>>(G, DpT, P);
  reduce_p<<<340, 256, 0, stream>>>(P, out);
}